// Round 5
// baseline (3884.949 us; speedup 1.0000x reference)
//
#include <hip/hip_runtime.h>
#include <math.h>

#define VOCAB 1000
#define EMB   128
#define HID   256
#define G4    1024   // 4*HID
#define BATCH 64
#define SEQT  1024
#define NBLK  4      // blocks per batch element (chunks)
#define MAGIC 0x13572468
// s_getreg immediate: ID=20 (HW_REG_XCC_ID), OFFSET=0, SIZE-1=3
#define GETREG_XCC ((20) | ((3) << 11))

__device__ __forceinline__ float sigmoidf_(float x) {
    return 1.f / (1.f + __expf(-x));
}
__device__ __forceinline__ float tanhf_(float x) {
    return 1.f - 2.f / (__expf(2.f * x) + 1.f);
}

// sc0: bypass L1, cacheable in the XCD's L2. Correct as the ONLY path when
// producer+consumer share an XCD (enforced dynamically below); otherwise the
// agent-scope mirror protocol takes over.
__device__ __forceinline__ void st_sc0(unsigned long long* p, unsigned long long v) {
    asm volatile("global_store_dwordx2 %0, %1, off sc0" :: "v"(p), "v"(v) : "memory");
}
__device__ __forceinline__ unsigned long long ld_sc0(const unsigned long long* p) {
    unsigned long long r;
    asm volatile("global_load_dwordx2 %0, %1, off sc0\n\t"
                 "s_waitcnt vmcnt(0)"
                 : "=&v"(r) : "v"(p) : "memory");
    return r;
}

// ---------------------------------------------------------------------------
// Kernel 1: eproj[v][g] = emb[v] . W_ih[g] + b_ih[g] + b_hh[g]
// ---------------------------------------------------------------------------
__global__ __launch_bounds__(1024) void eproj_kernel(
    const float* __restrict__ emb, const float* __restrict__ W_ih,
    const float* __restrict__ b_ih, const float* __restrict__ b_hh,
    float* __restrict__ eproj)
{
    const int v = blockIdx.x;
    const int g = threadIdx.x;
    __shared__ __align__(16) float x_sh[EMB];
    if (g < EMB / 4) {
        ((float4*)x_sh)[g] = ((const float4*)(emb + (size_t)v * EMB))[g];
    }
    __syncthreads();
    const float4* wrow = (const float4*)(W_ih + (size_t)g * EMB);
    float a0 = 0.f, a1 = 0.f, a2 = 0.f, a3 = 0.f;
#pragma unroll
    for (int e4 = 0; e4 < EMB / 4; e4++) {
        float4 wv = wrow[e4];
        float4 xv = ((const float4*)x_sh)[e4];
        a0 += wv.x * xv.x;
        a1 += wv.y * xv.y;
        a2 += wv.z * xv.z;
        a3 += wv.w * xv.w;
    }
    eproj[(size_t)v * G4 + g] = (a0 + a1) + (a2 + a3) + b_ih[g] + b_hh[g];
}

// ---------------------------------------------------------------------------
// Kernel 2: dynamic-XCD-grouped persistent LSTM.
// 256 blocks (1/CU, co-resident by register budget). Each block reads its
// physical XCC_ID, registers in ws, and groups of 4 same-XCD blocks are formed
// dynamically -> the per-step h exchange is an L2 hit (sc0), ~200cyc RT
// instead of ~2700cyc via MALL. Agent-scope mirror + tag-validated republish
// + sticky demotion guarantee correctness if anything about that fails.
// ---------------------------------------------------------------------------
__global__ __launch_bounds__(256, 1) void lstm_dyn_kernel(
    const int* __restrict__ ids, const int* __restrict__ lens,
    const float* __restrict__ eproj, const float* __restrict__ W_hh,
    unsigned int* __restrict__ coord,        // [0..7]=per-XCD cnt, [8]=total
    int* __restrict__ initflag,              // [BATCH][NBLK]
    unsigned long long* __restrict__ fastq,  // [2][BATCH][HID] packed (tag,h)
    unsigned long long* __restrict__ slowq,  // [2][BATCH][HID] packed (tag,h)
    float* __restrict__ out)
{
    const int j  = threadIdx.x;    // 0..255

    __shared__ int sh_b, sh_s, sh_fast;

    // ---- phase 0: dynamic XCD-aware group formation ----
    if (j == 0) {
        unsigned xcd = __builtin_amdgcn_s_getreg(GETREG_XCC) & 7u;
        unsigned slot = __hip_atomic_fetch_add(&coord[xcd], 1u,
                            __ATOMIC_RELAXED, __HIP_MEMORY_SCOPE_AGENT);
        __hip_atomic_fetch_add(&coord[8], 1u,
                            __ATOMIC_RELEASE, __HIP_MEMORY_SCOPE_AGENT);
        while (__hip_atomic_load(&coord[8], __ATOMIC_ACQUIRE,
                                 __HIP_MEMORY_SCOPE_AGENT) < (unsigned)(BATCH * NBLK)) {
            __builtin_amdgcn_s_sleep(8);
        }
        unsigned cnt[8];
        for (int y = 0; y < 8; y++)
            cnt[y] = __hip_atomic_load(&coord[y], __ATOMIC_RELAXED,
                                       __HIP_MEMORY_SCOPE_AGENT);
        int fulltot = 0, basex = 0;
        for (int y = 0; y < 8; y++) fulltot += (int)(cnt[y] >> 2);
        for (unsigned y = 0; y < xcd; y++) basex += (int)(cnt[y] >> 2);
        int grp, ch, fast;
        if (slot < (cnt[xcd] & ~3u)) {           // member of a full same-XCD group
            grp = basex + (int)(slot >> 2);
            ch  = (int)(slot & 3u);
            fast = 1;
        } else {                                  // leftover: cross-XCD group
            int rank = 0;
            for (unsigned y = 0; y < xcd; y++) rank += (int)(cnt[y] & 3u);
            rank += (int)(slot - (cnt[xcd] & ~3u));
            grp = fulltot + (rank >> 2);
            ch  = rank & 3;
            fast = 0;
        }
        sh_b = grp; sh_s = ch; sh_fast = fast;
    }
    __syncthreads();

    const int b     = sh_b;        // batch element this group owns
    const int s     = sh_s;        // chunk 0..3
    const int fastg = sh_fast;     // co-XCD group -> sc0 exchange
    const int gt    = j >> 6;      // gate type 0..3 (i,f,g,o)
    const int ul    = j & 63;      // unit-local 0..63
    const int r     = (gt << 8) | (s << 6) | ul;   // gate row 0..1023

    __shared__ __align__(16) float h_sh[HID];
    __shared__ __align__(16) float gates_sh[256];
    __shared__ unsigned long long pk_hist[2][64];  // my block's last publishes
    __shared__ int park_cnt;

    // W_hh row r -> registers (AGPR-backed on the unified file, no scratch)
    float w[HID];
    {
        const float4* wrow = (const float4*)(W_hh + (size_t)r * HID);
#pragma unroll
        for (int k4 = 0; k4 < HID / 4; k4++) {
            float4 wv = wrow[k4];
            w[4 * k4 + 0] = wv.x;
            w[4 * k4 + 1] = wv.y;
            w[4 * k4 + 2] = wv.z;
            w[4 * k4 + 3] = wv.w;
        }
    }

    const int len = lens[b];
    const int* ids_row = ids + (size_t)b * SEQT;

    h_sh[j] = 0.f;
    if (j < 128) ((unsigned long long*)pk_hist)[j] = 0ull;
    if (j == 0) park_cnt = fastg ? 0 : 1000;   // leftover groups: slow-only
    float c = 0.f;         // live in wave gt==s
    float hlast = 0.f;

    float xw = eproj[(size_t)ids_row[0] * G4 + r];

    unsigned long long* fast_b = fastq + (size_t)b * HID;
    unsigned long long* slow_b = slowq + (size_t)b * HID;
    const size_t par = (size_t)BATCH * HID;

    // ---- stale-L2 kill + init handshake (fast groups) ----
    if (fastg) {
        if (gt == s) {
            st_sc0(&fast_b[(s << 6) | ul], 0ull);
            st_sc0(&fast_b[par + ((s << 6) | ul)], 0ull);
            asm volatile("s_waitcnt vmcnt(0)" ::: "memory");
        }
        __syncthreads();
        if (j == 0) {
            __hip_atomic_store(&initflag[b * NBLK + s], MAGIC,
                               __ATOMIC_RELEASE, __HIP_MEMORY_SCOPE_AGENT);
        }
        if (j < NBLK && j != s) {
            while (__hip_atomic_load(&initflag[b * NBLK + j], __ATOMIC_ACQUIRE,
                                     __HIP_MEMORY_SCOPE_AGENT) != MAGIC) {
                __builtin_amdgcn_s_sleep(2);
            }
        }
    }
    __syncthreads();

    for (int step = 0; step < len; step++) {
        // prefetch next step's input projection (hides under the k-loop)
        const int nstep = (step + 1 < len) ? step + 1 : len - 1;
        const float xw_next = eproj[(size_t)ids_row[nstep] * G4 + r];

        // ---- P1: gates = xw + w . h  (h broadcast float4 from LDS) ----
        float a0 = xw, a1 = 0.f, a2 = 0.f, a3 = 0.f;
#pragma unroll
        for (int k4 = 0; k4 < HID / 4; k4++) {
            float4 hv = ((const float4*)h_sh)[k4];
            a0 += w[4 * k4 + 0] * hv.x;
            a1 += w[4 * k4 + 1] * hv.y;
            a2 += w[4 * k4 + 2] * hv.z;
            a3 += w[4 * k4 + 3] * hv.w;
        }
        gates_sh[j] = (a0 + a1) + (a2 + a3);
        __syncthreads();

        // ---- P2: activation + exchange ----
        const bool last = (step + 1 >= len);
        const int  pi   = step & 1;
        const bool blk_fast = fastg &&
            (__hip_atomic_load(&park_cnt, __ATOMIC_RELAXED,
                               __HIP_MEMORY_SCOPE_WORKGROUP) < 3);
        unsigned long long* fq = fast_b + (size_t)pi * par;
        unsigned long long* sq = slow_b + (size_t)pi * par;

        if (gt == s) {
            float ig = sigmoidf_(gates_sh[ul]);
            float fg = sigmoidf_(gates_sh[64 + ul]);
            float gg = tanhf_(gates_sh[128 + ul]);
            float og = sigmoidf_(gates_sh[192 + ul]);
            c = fg * c + ig * gg;
            float h = og * tanhf_(c);
            hlast = h;
            h_sh[(s << 6) | ul] = h;
            if (!last) {
                union { float f; unsigned u; } cv; cv.f = h;
                unsigned long long pk =
                    ((unsigned long long)(unsigned)(step + 1) << 32) | cv.u;
                pk_hist[pi][ul] = pk;
                st_sc0(&fq[(s << 6) | ul], pk);
                if (!blk_fast) {
                    __hip_atomic_store(&sq[(s << 6) | ul], pk,
                                       __ATOMIC_RELAXED, __HIP_MEMORY_SCOPE_AGENT);
                }
            }
        } else if (!last) {
            const unsigned want = (unsigned)(step + 1);
            unsigned long long v = 0;
            bool got = false;
            if (blk_fast) {
                // bounded L2-hit poll; healthy case: 1-3 iterations
                for (int it = 0; it < 32; ++it) {
                    if (!got) {
                        v = ld_sc0(&fq[(gt << 6) | ul]);
                        got = ((unsigned)(v >> 32) == want);
                    }
                    if (__all((int)got)) break;
                }
                if (!__all((int)got) && ul == 0) atomicAdd(&park_cnt, 1);
            }
            int rounds = 0;
            while (!__all((int)got)) {     // guaranteed-correct recovery path
                if (!got) {
                    v = __hip_atomic_load(&sq[(gt << 6) | ul],
                                          __ATOMIC_RELAXED, __HIP_MEMORY_SCOPE_AGENT);
                    got = ((unsigned)(v >> 32) == want);
                }
                if (!got && fastg) {
                    v = ld_sc0(&fq[(gt << 6) | ul]);
                    got = ((unsigned)(v >> 32) == want);
                }
                if ((++rounds & 15) == 0) {
                    // help partners: republish MY block's live publishes to the
                    // mirror (tag-validated; all 64 lanes; idempotent)
#pragma unroll
                    for (int p = 0; p < 2; p++) {
                        unsigned long long ph = pk_hist[p][ul];
                        if ((unsigned)(ph >> 32) != 0u) {
                            __hip_atomic_store(&slow_b[(size_t)p * par + ((s << 6) | ul)],
                                               ph, __ATOMIC_RELAXED,
                                               __HIP_MEMORY_SCOPE_AGENT);
                        }
                    }
                }
                __builtin_amdgcn_s_sleep(2);
            }
            union { unsigned u; float f; } cv; cv.u = (unsigned)v;
            h_sh[(gt << 6) | ul] = cv.f;
        }
        __syncthreads();
        xw = xw_next;
    }

    if (gt == s) {
        out[(size_t)b * HID + ((s << 6) | ul)] = hlast;
    }
}

// ---------------------------------------------------------------------------
// Fallback (ws too small): correct-but-slow single-block version.
// ---------------------------------------------------------------------------
__global__ __launch_bounds__(1024, 1) void lstm_fallback(
    const int* __restrict__ ids, const int* __restrict__ lens,
    const float* __restrict__ emb, const float* __restrict__ W_ih,
    const float* __restrict__ b_ih, const float* __restrict__ b_hh,
    const float* __restrict__ W_hh, float* __restrict__ out)
{
    const int b = blockIdx.x;
    const int t = threadIdx.x;

    __shared__ __align__(16) float h_sh[HID];
    __shared__ __align__(16) float c_sh[HID];
    __shared__ __align__(16) float gates[G4];
    __shared__ __align__(16) float x_sh[EMB];

    float wih[EMB];
    {
        const float4* wr = (const float4*)(W_ih + (size_t)t * EMB);
#pragma unroll
        for (int e4 = 0; e4 < EMB / 4; e4++) {
            float4 wv = wr[e4];
            wih[4 * e4 + 0] = wv.x;
            wih[4 * e4 + 1] = wv.y;
            wih[4 * e4 + 2] = wv.z;
            wih[4 * e4 + 3] = wv.w;
        }
    }
    float bias = b_ih[t] + b_hh[t];

    const int len = lens[b];
    const int* ids_row = ids + (size_t)b * SEQT;
    if (t < HID) { h_sh[t] = 0.f; c_sh[t] = 0.f; }
    __syncthreads();

    for (int step = 0; step < len; step++) {
        int id = ids_row[step];
        if (t < EMB / 4) {
            ((float4*)x_sh)[t] = ((const float4*)(emb + (size_t)id * EMB))[t];
        }
        __syncthreads();
        float a0 = bias, a1 = 0.f, a2 = 0.f, a3 = 0.f;
#pragma unroll
        for (int e4 = 0; e4 < EMB / 4; e4++) {
            float4 xv = ((const float4*)x_sh)[e4];
            a0 += wih[4 * e4 + 0] * xv.x;
            a1 += wih[4 * e4 + 1] * xv.y;
            a2 += wih[4 * e4 + 2] * xv.z;
            a3 += wih[4 * e4 + 3] * xv.w;
        }
        float acc = (a0 + a1) + (a2 + a3);

        const float* wrow = W_hh + (size_t)t * HID;
        a0 = acc; a1 = 0.f; a2 = 0.f; a3 = 0.f;
        for (int k4 = 0; k4 < HID / 4; k4++) {
            float4 hv = ((const float4*)h_sh)[k4];
            float4 wv = ((const float4*)wrow)[k4];
            a0 += wv.x * hv.x;
            a1 += wv.y * hv.y;
            a2 += wv.z * hv.z;
            a3 += wv.w * hv.w;
        }
        gates[t] = (a0 + a1) + (a2 + a3);
        __syncthreads();

        if (t < HID) {
            float ig = sigmoidf_(gates[t]);
            float fg = sigmoidf_(gates[HID + t]);
            float gg = tanhf_(gates[2 * HID + t]);
            float og = sigmoidf_(gates[3 * HID + t]);
            float cc = fg * c_sh[t] + ig * gg;
            c_sh[t] = cc;
            h_sh[t] = og * tanhf_(cc);
        }
        __syncthreads();
    }
    if (t < HID) out[(size_t)b * HID + t] = h_sh[t];
}

extern "C" void kernel_launch(void* const* d_in, const int* in_sizes, int n_in,
                              void* d_out, int out_size, void* d_ws, size_t ws_size,
                              hipStream_t stream) {
    const int*   ids  = (const int*)d_in[0];
    const int*   lens = (const int*)d_in[1];
    const float* emb  = (const float*)d_in[2];
    const float* Wih  = (const float*)d_in[3];
    const float* Whh  = (const float*)d_in[4];
    const float* bih  = (const float*)d_in[5];
    const float* bhh  = (const float*)d_in[6];
    float* out = (float*)d_out;

    // ws layout: coord+initflag (4 KB, zeroed) | fastq 256KB | slowq 256KB | eproj 4MB
    const size_t buf_bytes = (size_t)2 * BATCH * HID * sizeof(unsigned long long);
    const size_t fast_off  = 4096;
    const size_t slow_off  = fast_off + buf_bytes;
    const size_t ep_off    = slow_off + buf_bytes;
    const size_t ep_bytes  = (size_t)VOCAB * G4 * sizeof(float);

    if (ws_size >= ep_off + ep_bytes) {
        unsigned int* coord = (unsigned int*)d_ws;                      // [0,64)
        int* initflag = (int*)((char*)d_ws + 64);                       // 1 KB
        unsigned long long* fastq = (unsigned long long*)((char*)d_ws + fast_off);
        unsigned long long* slowq = (unsigned long long*)((char*)d_ws + slow_off);
        float* eproj = (float*)((char*)d_ws + ep_off);
        hipMemsetAsync(d_ws, 0, 64 + BATCH * NBLK * sizeof(int), stream);
        eproj_kernel<<<VOCAB, 1024, 0, stream>>>(emb, Wih, bih, bhh, eproj);
        lstm_dyn_kernel<<<BATCH * NBLK, 256, 0, stream>>>(
            ids, lens, eproj, Whh, coord, initflag, fastq, slowq, out);
    } else {
        lstm_fallback<<<BATCH, 1024, 0, stream>>>(
            ids, lens, emb, Wih, bih, bhh, Whh, out);
    }
}

// Round 6
// 2325.745 us; speedup vs baseline: 1.6704x; 1.6704x over previous
//
#include <hip/hip_runtime.h>
#include <math.h>

#define VOCAB 1000
#define EMB   128
#define HID   256
#define G4    1024   // 4*HID
#define BATCH 64
#define SEQT  1024
#define NBLK  4      // blocks per batch element (chunks)

__device__ __forceinline__ float sigmoidf_(float x) {
    return 1.f / (1.f + __expf(-x));
}
__device__ __forceinline__ float tanhf_(float x) {
    return 1.f - 2.f / (__expf(2.f * x) + 1.f);
}

// 64-weight segment ops with COMPILE-TIME register offsets (runtime chunk ids
// only appear in LDS/global addresses, never as register-array indices).
template <int OFF>
__device__ __forceinline__ void load_seg(float (&w)[HID], const float* src) {
#pragma unroll
    for (int k4 = 0; k4 < 16; k4++) {
        float4 wv = ((const float4*)src)[k4];
        w[OFF + 4 * k4 + 0] = wv.x;
        w[OFF + 4 * k4 + 1] = wv.y;
        w[OFF + 4 * k4 + 2] = wv.z;
        w[OFF + 4 * k4 + 3] = wv.w;
    }
}
template <int OFF>
__device__ __forceinline__ void fma_seg(const float (&w)[HID], const float* hb,
                                        float& a0, float& a1, float& a2, float& a3) {
#pragma unroll
    for (int k4 = 0; k4 < 16; k4++) {
        float4 hv = ((const float4*)hb)[k4];   // broadcast, conflict-free
        a0 += w[OFF + 4 * k4 + 0] * hv.x;
        a1 += w[OFF + 4 * k4 + 1] * hv.y;
        a2 += w[OFF + 4 * k4 + 2] * hv.z;
        a3 += w[OFF + 4 * k4 + 3] * hv.w;
    }
}

__device__ __forceinline__ void spin_flag(const int* f, int want) {
    while (__hip_atomic_load(f, __ATOMIC_ACQUIRE,
                             __HIP_MEMORY_SCOPE_WORKGROUP) != want) {}
}

// ---------------------------------------------------------------------------
// Kernel 1: eproj[v][g] = emb[v] . W_ih[g] + b_ih[g] + b_hh[g]
// ---------------------------------------------------------------------------
__global__ __launch_bounds__(1024) void eproj_kernel(
    const float* __restrict__ emb, const float* __restrict__ W_ih,
    const float* __restrict__ b_ih, const float* __restrict__ b_hh,
    float* __restrict__ eproj)
{
    const int v = blockIdx.x;
    const int g = threadIdx.x;
    __shared__ __align__(16) float x_sh[EMB];
    if (g < EMB / 4) {
        ((float4*)x_sh)[g] = ((const float4*)(emb + (size_t)v * EMB))[g];
    }
    __syncthreads();
    const float4* wrow = (const float4*)(W_ih + (size_t)g * EMB);
    float a0 = 0.f, a1 = 0.f, a2 = 0.f, a3 = 0.f;
#pragma unroll
    for (int e4 = 0; e4 < EMB / 4; e4++) {
        float4 wv = wrow[e4];
        float4 xv = ((const float4*)x_sh)[e4];
        a0 += wv.x * xv.x;
        a1 += wv.y * xv.y;
        a2 += wv.z * xv.z;
        a3 += wv.w * xv.w;
    }
    eproj[(size_t)v * G4 + g] = (a0 + a1) + (a2 + a3) + b_ih[g] + b_hh[g];
}

// ---------------------------------------------------------------------------
// Kernel 2: latency-pipelined 4-block LSTM group.
// Per step the ONLY serial remote dependency is one packed (tag,h) store →
// poll round. All local compute (own-chunk FMA, sibling-chunk FMAs) is
// overlapped INTO that latency window via per-chunk LDS flags; 1 barrier/step.
// Weight registers are permuted per-thread into processing order so register
// indices stay compile-time.
// ---------------------------------------------------------------------------
__global__ __launch_bounds__(256, 1) void lstm_group_kernel(
    const int* __restrict__ ids, const int* __restrict__ lens,
    const float* __restrict__ eproj, const float* __restrict__ W_hh,
    unsigned long long* __restrict__ q,   // [2][BATCH][HID] packed (tag,h)
    float* __restrict__ out)
{
    const int idx  = blockIdx.x;
    const int xcd  = idx & 7;
    const int m    = idx >> 3;
    const int s    = m & 3;          // my chunk 0..3
    const int slot = m >> 2;
    const int b    = xcd + 8 * slot; // batch element

    const int j  = threadIdx.x;      // 0..255
    const int gt = j >> 6;           // wave id = gate type = polled chunk
    const int ul = j & 63;
    const int r  = (gt << 8) | (s << 6) | ul;   // my gate row
    const bool prod = (gt == s);

    // processing order: own chunk s first; consumers do their polled chunk
    // second; remainder ascending.
    int o1, o2, o3;
    if (prod) {
        o1 = (s + 1) & 3; o2 = (s + 2) & 3; o3 = (s + 3) & 3;
    } else {
        o1 = gt;
        int a = -1, bb = -1;
        for (int t4 = 0; t4 < 4; t4++)
            if (t4 != s && t4 != gt) { if (a < 0) a = t4; else bb = t4; }
        o2 = a; o3 = bb;
    }

    __shared__ __align__(16) float h_sh[HID];
    __shared__ __align__(16) float gates_sh[2][256];  // parity double-buffer
    __shared__ int flag[4];   // flag[q]==t  <=>  h(t) chunk q is in h_sh

    // weights permuted into processing order (AGPR-backed, no scratch)
    float w[HID];
    {
        const float* wrow = W_hh + (size_t)r * HID;
        load_seg<0>  (w, wrow + (s  << 6));
        load_seg<64> (w, wrow + (o1 << 6));
        load_seg<128>(w, wrow + (o2 << 6));
        load_seg<192>(w, wrow + (o3 << 6));
    }

    const int len = lens[b];
    const int* idr = ids + (size_t)b * SEQT;

    h_sh[j] = 0.f;                    // h(0) = 0, all chunks
    if (j < 4) flag[j] = 0;           // tag 0 = "h(0) ready"
    float c = 0.f, hlast = 0.f;

    float xw = eproj[(size_t)idr[0] * G4 + r];
    __syncthreads();

    unsigned long long* qb = q + (size_t)b * HID;
    const size_t par = (size_t)BATCH * HID;

    for (int t = 0; t < len; t++) {
        const int nt = (t + 1 < len) ? t + 1 : len - 1;
        const float xwn = eproj[(size_t)idr[nt] * G4 + r];   // prefetch

        const int p = t & 1;
        float a0 = xw, a1 = 0.f, a2 = 0.f, a3 = 0.f;

        if (prod || t == 0) {
            // all chunks via LDS (t==0: everything preset; producer: siblings
            // fill chunks as their polls land)
            spin_flag(&flag[s], t);  fma_seg<0>  (w, h_sh + (s  << 6), a0, a1, a2, a3);
            spin_flag(&flag[o1], t); fma_seg<64> (w, h_sh + (o1 << 6), a0, a1, a2, a3);
            spin_flag(&flag[o2], t); fma_seg<128>(w, h_sh + (o2 << 6), a0, a1, a2, a3);
            spin_flag(&flag[o3], t); fma_seg<192>(w, h_sh + (o3 << 6), a0, a1, a2, a3);
        } else {
            // consumer wave: issue remote poll FIRST, hide own-chunk FMA
            // under the flight time, then chase the tag.
            const unsigned long long* gp = qb + (size_t)p * par + ((gt << 6) | ul);
            unsigned long long v = __hip_atomic_load(gp, __ATOMIC_RELAXED,
                                                     __HIP_MEMORY_SCOPE_AGENT);
            spin_flag(&flag[s], t);
            fma_seg<0>(w, h_sh + (s << 6), a0, a1, a2, a3);
            while ((unsigned)(v >> 32) != (unsigned)t) {
                v = __hip_atomic_load(gp, __ATOMIC_RELAXED,
                                      __HIP_MEMORY_SCOPE_AGENT);
            }
            union { unsigned u; float f; } cv; cv.u = (unsigned)v;
            h_sh[(gt << 6) | ul] = cv.f;
            __threadfence_block();
            if (ul == 0)
                __hip_atomic_store(&flag[gt], t, __ATOMIC_RELEASE,
                                   __HIP_MEMORY_SCOPE_WORKGROUP);
            fma_seg<64>(w, h_sh + (o1 << 6), a0, a1, a2, a3);   // o1 == gt
            spin_flag(&flag[o2], t); fma_seg<128>(w, h_sh + (o2 << 6), a0, a1, a2, a3);
            spin_flag(&flag[o3], t); fma_seg<192>(w, h_sh + (o3 << 6), a0, a1, a2, a3);
        }

        gates_sh[p][j] = (a0 + a1) + (a2 + a3);
        __syncthreads();   // the ONE barrier per step

        if (prod) {
            float ig = sigmoidf_(gates_sh[p][ul]);
            float fg = sigmoidf_(gates_sh[p][64 + ul]);
            float gg = tanhf_(gates_sh[p][128 + ul]);
            float og = sigmoidf_(gates_sh[p][192 + ul]);
            c = fg * c + ig * gg;
            float h = og * tanhf_(c);
            hlast = h;
            if (t + 1 < len) {
                union { float f; unsigned u; } cu; cu.f = h;
                unsigned long long pk =
                    ((unsigned long long)(unsigned)(t + 1) << 32) | cu.u;
                // publish remote copy ASAP (latency-critical)...
                __hip_atomic_store(qb + (size_t)((t + 1) & 1) * par + ((s << 6) | ul),
                                   pk, __ATOMIC_RELAXED, __HIP_MEMORY_SCOPE_AGENT);
                // ...then local copy + flag
                h_sh[(s << 6) | ul] = h;
                __threadfence_block();
                if (ul == 0)
                    __hip_atomic_store(&flag[s], t + 1, __ATOMIC_RELEASE,
                                       __HIP_MEMORY_SCOPE_WORKGROUP);
            }
        }
        xw = xwn;
    }

    if (prod) out[(size_t)b * HID + ((s << 6) | ul)] = hlast;
}

// ---------------------------------------------------------------------------
// Fallback (ws too small): correct-but-slow single-block version.
// ---------------------------------------------------------------------------
__global__ __launch_bounds__(1024, 1) void lstm_fallback(
    const int* __restrict__ ids, const int* __restrict__ lens,
    const float* __restrict__ emb, const float* __restrict__ W_ih,
    const float* __restrict__ b_ih, const float* __restrict__ b_hh,
    const float* __restrict__ W_hh, float* __restrict__ out)
{
    const int b = blockIdx.x;
    const int t = threadIdx.x;

    __shared__ __align__(16) float h_sh[HID];
    __shared__ __align__(16) float c_sh[HID];
    __shared__ __align__(16) float gates[G4];
    __shared__ __align__(16) float x_sh[EMB];

    float wih[EMB];
    {
        const float4* wr = (const float4*)(W_ih + (size_t)t * EMB);
#pragma unroll
        for (int e4 = 0; e4 < EMB / 4; e4++) {
            float4 wv = wr[e4];
            wih[4 * e4 + 0] = wv.x;
            wih[4 * e4 + 1] = wv.y;
            wih[4 * e4 + 2] = wv.z;
            wih[4 * e4 + 3] = wv.w;
        }
    }
    float bias = b_ih[t] + b_hh[t];

    const int len = lens[b];
    const int* ids_row = ids + (size_t)b * SEQT;
    if (t < HID) { h_sh[t] = 0.f; c_sh[t] = 0.f; }
    __syncthreads();

    for (int step = 0; step < len; step++) {
        int id = ids_row[step];
        if (t < EMB / 4) {
            ((float4*)x_sh)[t] = ((const float4*)(emb + (size_t)id * EMB))[t];
        }
        __syncthreads();
        float a0 = bias, a1 = 0.f, a2 = 0.f, a3 = 0.f;
#pragma unroll
        for (int e4 = 0; e4 < EMB / 4; e4++) {
            float4 xv = ((const float4*)x_sh)[e4];
            a0 += wih[4 * e4 + 0] * xv.x;
            a1 += wih[4 * e4 + 1] * xv.y;
            a2 += wih[4 * e4 + 2] * xv.z;
            a3 += wih[4 * e4 + 3] * xv.w;
        }
        float acc = (a0 + a1) + (a2 + a3);

        const float* wrow = W_hh + (size_t)t * HID;
        a0 = acc; a1 = 0.f; a2 = 0.f; a3 = 0.f;
        for (int k4 = 0; k4 < HID / 4; k4++) {
            float4 hv = ((const float4*)h_sh)[k4];
            float4 wv = ((const float4*)wrow)[k4];
            a0 += wv.x * hv.x;
            a1 += wv.y * hv.y;
            a2 += wv.z * hv.z;
            a3 += wv.w * hv.w;
        }
        gates[t] = (a0 + a1) + (a2 + a3);
        __syncthreads();

        if (t < HID) {
            float ig = sigmoidf_(gates[t]);
            float fg = sigmoidf_(gates[HID + t]);
            float gg = tanhf_(gates[2 * HID + t]);
            float og = sigmoidf_(gates[3 * HID + t]);
            float cc = fg * c_sh[t] + ig * gg;
            c_sh[t] = cc;
            h_sh[t] = og * tanhf_(cc);
        }
        __syncthreads();
    }
    if (t < HID) out[(size_t)b * HID + t] = h_sh[t];
}

extern "C" void kernel_launch(void* const* d_in, const int* in_sizes, int n_in,
                              void* d_out, int out_size, void* d_ws, size_t ws_size,
                              hipStream_t stream) {
    const int*   ids  = (const int*)d_in[0];
    const int*   lens = (const int*)d_in[1];
    const float* emb  = (const float*)d_in[2];
    const float* Wih  = (const float*)d_in[3];
    const float* Whh  = (const float*)d_in[4];
    const float* bih  = (const float*)d_in[5];
    const float* bhh  = (const float*)d_in[6];
    float* out = (float*)d_out;

    // ws layout: q[2][64][256] packed u64 (256 KB) | eproj (4 MB)
    const size_t q_bytes  = (size_t)2 * BATCH * HID * sizeof(unsigned long long);
    const size_t ep_off   = q_bytes;
    const size_t ep_bytes = (size_t)VOCAB * G4 * sizeof(float);

    if (ws_size >= ep_off + ep_bytes) {
        unsigned long long* qq = (unsigned long long*)d_ws;
        float* eproj = (float*)((char*)d_ws + ep_off);
        eproj_kernel<<<VOCAB, 1024, 0, stream>>>(emb, Wih, bih, bhh, eproj);
        lstm_group_kernel<<<BATCH * NBLK, 256, 0, stream>>>(
            ids, lens, eproj, Whh, qq, out);
    } else {
        lstm_fallback<<<BATCH, 1024, 0, stream>>>(
            ids, lens, emb, Wih, bih, bhh, Whh, out);
    }
}

// Round 8
// 2248.243 us; speedup vs baseline: 1.7280x; 1.0345x over previous
//
#include <hip/hip_runtime.h>
#include <math.h>

#define VOCAB 1000
#define EMB   128
#define HID   256
#define G4    1024   // 4*HID
#define BATCH 64
#define SEQT  1024
#define NBLK  4      // blocks per batch element (chunks)

typedef unsigned long long u64;
typedef __attribute__((ext_vector_type(4))) unsigned int uint4v;

__device__ __forceinline__ float sigmoidf_(float x) {
    return 1.f / (1.f + __expf(-x));
}
__device__ __forceinline__ float tanhf_(float x) {
    return 1.f - 2.f / (__expf(2.f * x) + 1.f);
}

// 16B agent-coherent load (bypass L1+L2 -> reads MALL, where agent-scope
// stores land). Returns two packed (tag,h) words; each 8B half is
// self-validating so 16B access atomicity is irrelevant.
__device__ __forceinline__ void ld16_sc(const u64* p, u64& a, u64& b) {
    uint4v r;
    asm volatile("global_load_dwordx4 %0, %1, off sc0 sc1\n\t"
                 "s_waitcnt vmcnt(0)"
                 : "=&v"(r) : "v"(p) : "memory");
    a = ((u64)r.y << 32) | r.x;
    b = ((u64)r.w << 32) | r.z;
}

// 64-weight segment ops with COMPILE-TIME register offsets (runtime chunk ids
// only appear in LDS/global addresses, never as register-array indices).
template <int OFF>
__device__ __forceinline__ void load_seg(float (&w)[HID], const float* src) {
#pragma unroll
    for (int k4 = 0; k4 < 16; k4++) {
        float4 wv = ((const float4*)src)[k4];
        w[OFF + 4 * k4 + 0] = wv.x;
        w[OFF + 4 * k4 + 1] = wv.y;
        w[OFF + 4 * k4 + 2] = wv.z;
        w[OFF + 4 * k4 + 3] = wv.w;
    }
}
template <int OFF>
__device__ __forceinline__ void fma_seg(const float (&w)[HID], const float* hb,
                                        float& a0, float& a1, float& a2, float& a3) {
#pragma unroll
    for (int k4 = 0; k4 < 16; k4++) {
        float4 hv = ((const float4*)hb)[k4];   // broadcast, conflict-free
        a0 += w[OFF + 4 * k4 + 0] * hv.x;
        a1 += w[OFF + 4 * k4 + 1] * hv.y;
        a2 += w[OFF + 4 * k4 + 2] * hv.z;
        a3 += w[OFF + 4 * k4 + 3] * hv.w;
    }
}

__device__ __forceinline__ void spin_flag(const int* f, int want) {
    while (__hip_atomic_load(f, __ATOMIC_ACQUIRE,
                             __HIP_MEMORY_SCOPE_WORKGROUP) != want) {}
}

// ---------------------------------------------------------------------------
// Kernel 1: eproj[v][g] = emb[v] . W_ih[g] + b_ih[g] + b_hh[g]
// ---------------------------------------------------------------------------
__global__ __launch_bounds__(1024) void eproj_kernel(
    const float* __restrict__ emb, const float* __restrict__ W_ih,
    const float* __restrict__ b_ih, const float* __restrict__ b_hh,
    float* __restrict__ eproj)
{
    const int v = blockIdx.x;
    const int g = threadIdx.x;
    __shared__ __align__(16) float x_sh[EMB];
    if (g < EMB / 4) {
        ((float4*)x_sh)[g] = ((const float4*)(emb + (size_t)v * EMB))[g];
    }
    __syncthreads();
    const float4* wrow = (const float4*)(W_ih + (size_t)g * EMB);
    float a0 = 0.f, a1 = 0.f, a2 = 0.f, a3 = 0.f;
#pragma unroll
    for (int e4 = 0; e4 < EMB / 4; e4++) {
        float4 wv = wrow[e4];
        float4 xv = ((const float4*)x_sh)[e4];
        a0 += wv.x * xv.x;
        a1 += wv.y * xv.y;
        a2 += wv.z * xv.z;
        a3 += wv.w * xv.w;
    }
    eproj[(size_t)v * G4 + g] = (a0 + a1) + (a2 + a3) + b_ih[g] + b_hh[g];
}

// ---------------------------------------------------------------------------
// Kernel 2: latency-pipelined 4-block LSTM group (R6 structure) with
// congestion-tamed polling: 32 lanes x dwordx4 (half the fabric ops) and
// s_sleep backoff on misses (first poll can't succeed; wasted polls queue in
// front of the producers' stores on the shared EA/MALL path).
// ---------------------------------------------------------------------------
__global__ __launch_bounds__(256, 1) void lstm_group_kernel(
    const int* __restrict__ ids, const int* __restrict__ lens,
    const float* __restrict__ eproj, const float* __restrict__ W_hh,
    u64* __restrict__ q,   // [2][BATCH][HID] packed (tag,h)
    float* __restrict__ out)
{
    const int idx  = blockIdx.x;
    const int xcd  = idx & 7;
    const int m    = idx >> 3;
    const int s    = m & 3;          // my chunk 0..3
    const int slot = m >> 2;
    const int b    = xcd + 8 * slot; // batch element

    const int j  = threadIdx.x;      // 0..255
    const int gt = j >> 6;           // wave id = gate type = polled chunk
    const int ul = j & 63;
    const int r  = (gt << 8) | (s << 6) | ul;   // my gate row
    const bool prod = (gt == s);

    // processing order: own chunk s first; consumers do their polled chunk
    // second; remainder ascending.
    int o1, o2, o3;
    if (prod) {
        o1 = (s + 1) & 3; o2 = (s + 2) & 3; o3 = (s + 3) & 3;
    } else {
        o1 = gt;
        int a = -1, bb = -1;
        for (int t4 = 0; t4 < 4; t4++)
            if (t4 != s && t4 != gt) { if (a < 0) a = t4; else bb = t4; }
        o2 = a; o3 = bb;
    }

    __shared__ __align__(16) float h_sh[HID];
    __shared__ __align__(16) float gates_sh[2][256];  // parity double-buffer
    __shared__ int flag[4];   // flag[q]==t  <=>  h(t) chunk q is in h_sh

    // weights permuted into processing order (AGPR-backed, no scratch)
    float w[HID];
    {
        const float* wrow = W_hh + (size_t)r * HID;
        load_seg<0>  (w, wrow + (s  << 6));
        load_seg<64> (w, wrow + (o1 << 6));
        load_seg<128>(w, wrow + (o2 << 6));
        load_seg<192>(w, wrow + (o3 << 6));
    }

    const int len = lens[b];
    const int* idr = ids + (size_t)b * SEQT;

    h_sh[j] = 0.f;                    // h(0) = 0, all chunks
    if (j < 4) flag[j] = 0;           // tag 0 = "h(0) ready"
    float c = 0.f, hlast = 0.f;

    float xw = eproj[(size_t)idr[0] * G4 + r];
    __syncthreads();

    u64* qb = q + (size_t)b * HID;
    const size_t par = (size_t)BATCH * HID;

    for (int t = 0; t < len; t++) {
        const int nt = (t + 1 < len) ? t + 1 : len - 1;
        const float xwn = eproj[(size_t)idr[nt] * G4 + r];   // prefetch

        const int p = t & 1;
        float a0 = xw, a1 = 0.f, a2 = 0.f, a3 = 0.f;

        if (prod || t == 0) {
            // all chunks via LDS (t==0: everything preset; producer: siblings
            // fill chunks as their polls land)
            spin_flag(&flag[s], t);  fma_seg<0>  (w, h_sh + (s  << 6), a0, a1, a2, a3);
            spin_flag(&flag[o1], t); fma_seg<64> (w, h_sh + (o1 << 6), a0, a1, a2, a3);
            spin_flag(&flag[o2], t); fma_seg<128>(w, h_sh + (o2 << 6), a0, a1, a2, a3);
            spin_flag(&flag[o3], t); fma_seg<192>(w, h_sh + (o3 << 6), a0, a1, a2, a3);
        } else {
            // consumer wave: own-chunk FMA first (it's ready), then paced
            // 16B polls from 32 lanes (half the fabric traffic of R6).
            spin_flag(&flag[s], t);
            fma_seg<0>(w, h_sh + (s << 6), a0, a1, a2, a3);

            const unsigned wantu = (unsigned)t;
            if (ul < 32) {
                const u64* gp2 = qb + (size_t)p * par + (gt << 6) + (ul << 1);
                u64 va, vb;
                ld16_sc(gp2, va, vb);
                int miss = 0;
                while (((unsigned)(va >> 32) != wantu) ||
                       ((unsigned)(vb >> 32) != wantu)) {
                    if (miss < 2) {
                        __builtin_amdgcn_s_sleep(1);   // constant immediates
                    } else {
                        __builtin_amdgcn_s_sleep(2);
                    }
                    ++miss;
                    ld16_sc(gp2, va, vb);
                }
                union { unsigned u; float f; } ca, cb;
                ca.u = (unsigned)va; cb.u = (unsigned)vb;
                h_sh[(gt << 6) + (ul << 1)]     = ca.f;
                h_sh[(gt << 6) + (ul << 1) + 1] = cb.f;
            }
            __threadfence_block();
            if (ul == 0)
                __hip_atomic_store(&flag[gt], t, __ATOMIC_RELEASE,
                                   __HIP_MEMORY_SCOPE_WORKGROUP);
            fma_seg<64>(w, h_sh + (o1 << 6), a0, a1, a2, a3);   // o1 == gt
            spin_flag(&flag[o2], t); fma_seg<128>(w, h_sh + (o2 << 6), a0, a1, a2, a3);
            spin_flag(&flag[o3], t); fma_seg<192>(w, h_sh + (o3 << 6), a0, a1, a2, a3);
        }

        gates_sh[p][j] = (a0 + a1) + (a2 + a3);
        __syncthreads();   // the ONE barrier per step

        if (prod) {
            float ig = sigmoidf_(gates_sh[p][ul]);
            float fg = sigmoidf_(gates_sh[p][64 + ul]);
            float gg = tanhf_(gates_sh[p][128 + ul]);
            float og = sigmoidf_(gates_sh[p][192 + ul]);
            c = fg * c + ig * gg;
            float h = og * tanhf_(c);
            hlast = h;
            if (t + 1 < len) {
                union { float f; unsigned u; } cu; cu.f = h;
                u64 pk = ((u64)(unsigned)(t + 1) << 32) | cu.u;
                // publish remote copy ASAP (latency-critical)...
                __hip_atomic_store(qb + (size_t)((t + 1) & 1) * par + ((s << 6) | ul),
                                   pk, __ATOMIC_RELAXED, __HIP_MEMORY_SCOPE_AGENT);
                // ...then local copy + flag
                h_sh[(s << 6) | ul] = h;
                __threadfence_block();
                if (ul == 0)
                    __hip_atomic_store(&flag[s], t + 1, __ATOMIC_RELEASE,
                                       __HIP_MEMORY_SCOPE_WORKGROUP);
            }
        }
        xw = xwn;
    }

    if (prod) out[(size_t)b * HID + ((s << 6) | ul)] = hlast;
}

// ---------------------------------------------------------------------------
// Fallback (ws too small): correct-but-slow single-block version.
// ---------------------------------------------------------------------------
__global__ __launch_bounds__(1024, 1) void lstm_fallback(
    const int* __restrict__ ids, const int* __restrict__ lens,
    const float* __restrict__ emb, const float* __restrict__ W_ih,
    const float* __restrict__ b_ih, const float* __restrict__ b_hh,
    const float* __restrict__ W_hh, float* __restrict__ out)
{
    const int b = blockIdx.x;
    const int t = threadIdx.x;

    __shared__ __align__(16) float h_sh[HID];
    __shared__ __align__(16) float c_sh[HID];
    __shared__ __align__(16) float gates[G4];
    __shared__ __align__(16) float x_sh[EMB];

    float wih[EMB];
    {
        const float4* wr = (const float4*)(W_ih + (size_t)t * EMB);
#pragma unroll
        for (int e4 = 0; e4 < EMB / 4; e4++) {
            float4 wv = wr[e4];
            wih[4 * e4 + 0] = wv.x;
            wih[4 * e4 + 1] = wv.y;
            wih[4 * e4 + 2] = wv.z;
            wih[4 * e4 + 3] = wv.w;
        }
    }
    float bias = b_ih[t] + b_hh[t];

    const int len = lens[b];
    const int* ids_row = ids + (size_t)b * SEQT;
    if (t < HID) { h_sh[t] = 0.f; c_sh[t] = 0.f; }
    __syncthreads();

    for (int step = 0; step < len; step++) {
        int id = ids_row[step];
        if (t < EMB / 4) {
            ((float4*)x_sh)[t] = ((const float4*)(emb + (size_t)id * EMB))[t];
        }
        __syncthreads();
        float a0 = bias, a1 = 0.f, a2 = 0.f, a3 = 0.f;
#pragma unroll
        for (int e4 = 0; e4 < EMB / 4; e4++) {
            float4 xv = ((const float4*)x_sh)[e4];
            a0 += wih[4 * e4 + 0] * xv.x;
            a1 += wih[4 * e4 + 1] * xv.y;
            a2 += wih[4 * e4 + 2] * xv.z;
            a3 += wih[4 * e4 + 3] * xv.w;
        }
        float acc = (a0 + a1) + (a2 + a3);

        const float* wrow = W_hh + (size_t)t * HID;
        a0 = acc; a1 = 0.f; a2 = 0.f; a3 = 0.f;
        for (int k4 = 0; k4 < HID / 4; k4++) {
            float4 hv = ((const float4*)h_sh)[k4];
            float4 wv = ((const float4*)wrow)[k4];
            a0 += wv.x * hv.x;
            a1 += wv.y * hv.y;
            a2 += wv.z * hv.z;
            a3 += wv.w * hv.w;
        }
        gates[t] = (a0 + a1) + (a2 + a3);
        __syncthreads();

        if (t < HID) {
            float ig = sigmoidf_(gates[t]);
            float fg = sigmoidf_(gates[HID + t]);
            float gg = tanhf_(gates[2 * HID + t]);
            float og = sigmoidf_(gates[3 * HID + t]);
            float cc = fg * c_sh[t] + ig * gg;
            c_sh[t] = cc;
            h_sh[t] = og * tanhf_(cc);
        }
        __syncthreads();
    }
    if (t < HID) out[(size_t)b * HID + t] = h_sh[t];
}

extern "C" void kernel_launch(void* const* d_in, const int* in_sizes, int n_in,
                              void* d_out, int out_size, void* d_ws, size_t ws_size,
                              hipStream_t stream) {
    const int*   ids  = (const int*)d_in[0];
    const int*   lens = (const int*)d_in[1];
    const float* emb  = (const float*)d_in[2];
    const float* Wih  = (const float*)d_in[3];
    const float* Whh  = (const float*)d_in[4];
    const float* bih  = (const float*)d_in[5];
    const float* bhh  = (const float*)d_in[6];
    float* out = (float*)d_out;

    // ws layout: q[2][64][256] packed u64 (256 KB) | eproj (4 MB)
    const size_t q_bytes  = (size_t)2 * BATCH * HID * sizeof(u64);
    const size_t ep_off   = q_bytes;
    const size_t ep_bytes = (size_t)VOCAB * G4 * sizeof(float);

    if (ws_size >= ep_off + ep_bytes) {
        u64* qq = (u64*)d_ws;
        float* eproj = (float*)((char*)d_ws + ep_off);
        eproj_kernel<<<VOCAB, 1024, 0, stream>>>(emb, Wih, bih, bhh, eproj);
        lstm_group_kernel<<<BATCH * NBLK, 256, 0, stream>>>(
            ids, lens, eproj, Whh, qq, out);
    } else {
        lstm_fallback<<<BATCH, 1024, 0, stream>>>(
            ids, lens, emb, Wih, bih, bhh, Whh, out);
    }
}